// Round 5
// baseline (147.147 us; speedup 1.0000x reference)
//
#include <hip/hip_runtime.h>
#include <math.h>

#define SEQ 576
#define DIM 192
#define INNER 384
#define NHEAD 96
#define HS 24
#define WSZ 24
#define GIN 1152

// 1) fused LayerNorm + up-proj GEMM: x_inner = LN(x) @ up_w.T + up_b
//    grid (9, 24): BM=64 rows x BN=32 outs. LN recomputed per block (cheap).
#define UPA 68
#define UPB 36
__global__ __launch_bounds__(256) void k_up(const float* __restrict__ x,
    const float* __restrict__ lnw, const float* __restrict__ lnb,
    const float* __restrict__ w, const float* __restrict__ b,
    float* __restrict__ out) {
  int m0 = blockIdx.x * 64, n0 = blockIdx.y * 32;
  __shared__ float As[DIM * UPA];   // [k][m] normalized x, transposed
  __shared__ float Bs[DIM * UPB];   // [k][o]
  int t = threadIdx.x;
  for (int idx = t; idx < 32 * DIM; idx += 256) {
    int r = idx / DIM, k = idx % DIM;
    Bs[k * UPB + r] = w[(n0 + r) * DIM + k];
  }
  // LN: 4 threads per row, 48 elems each, quad shuffle reduce
  {
    int r = t >> 2, g = t & 3;
    const float* xr = x + (m0 + r) * DIM + g * 48;
    float xv[48];
    float sum = 0.f;
    #pragma unroll
    for (int j = 0; j < 48; ++j) { xv[j] = xr[j]; sum += xv[j]; }
    sum += __shfl_xor(sum, 1);
    sum += __shfl_xor(sum, 2);
    float mu = sum * (1.0f / DIM);
    float vsum = 0.f;
    #pragma unroll
    for (int j = 0; j < 48; ++j) { float d = xv[j] - mu; vsum += d * d; }
    vsum += __shfl_xor(vsum, 1);
    vsum += __shfl_xor(vsum, 2);
    float inv = rsqrtf(vsum * (1.0f / DIM) + 1e-5f);
    #pragma unroll
    for (int j = 0; j < 48; ++j) {
      int k = g * 48 + j;
      As[k * UPA + r] = (xv[j] - mu) * inv * lnw[k] + lnb[k];
    }
  }
  __syncthreads();
  int gm = t >> 4;        // 0..15 -> tokens 4gm..+3
  int gn = t & 15;        // 0..15 -> outputs 2gn..+1
  float acc[4][2];
  #pragma unroll
  for (int i = 0; i < 4; ++i)
    #pragma unroll
    for (int j = 0; j < 2; ++j) acc[i][j] = b[n0 + 2 * gn + j];
  #pragma unroll 4
  for (int kk = 0; kk < DIM; ++kk) {
    float4 a = *(const float4*)&As[kk * UPA + 4 * gm];
    float2 bv = *(const float2*)&Bs[kk * UPB + 2 * gn];
    acc[0][0] += a.x * bv.x; acc[0][1] += a.x * bv.y;
    acc[1][0] += a.y * bv.x; acc[1][1] += a.y * bv.y;
    acc[2][0] += a.z * bv.x; acc[2][1] += a.z * bv.y;
    acc[3][0] += a.w * bv.x; acc[3][1] += a.w * bv.y;
  }
  #pragma unroll
  for (int i = 0; i < 4; ++i) {
    float2 v = make_float2(acc[i][0], acc[i][1]);
    *(float2*)&out[(m0 + 4 * gm + i) * (2 * INNER) + n0 + 2 * gn] = v;
  }
}

// 2) fused depthwise 3x3 conv + SiLU + headwise qkv -> xa (row-major) and
//    ginT [1152][576] with coalesced 16-wide writes.
//    grid (36 token-tiles of 16, 2 channel-halves of 192), 256 threads.
#define QTOK 16
#define QPAD 193
__global__ __launch_bounds__(256) void k_cqkv(const float* __restrict__ xin,
    const float* __restrict__ cw, const float* __restrict__ cb,
    const float* __restrict__ qw, const float* __restrict__ qb,
    const float* __restrict__ kw, const float* __restrict__ kb,
    const float* __restrict__ vw, const float* __restrict__ vb,
    float* __restrict__ xa, float* __restrict__ ginT) {
  int s0 = blockIdx.x * QTOK;
  int c0 = blockIdx.y * 192;
  __shared__ float xat[QTOK][QPAD];   // conv+silu result [token][ch]
  __shared__ float xmt[QTOK][QPAD];   // x_mlstm tile (V input)
  __shared__ float qws[48 * 16], kws[48 * 16], vws[48 * 16];
  int t = threadIdx.x;
  for (int idx = t; idx < 48 * 16; idx += 256) {
    qws[idx] = qw[blockIdx.y * 768 + idx];
    kws[idx] = kw[blockIdx.y * 768 + idx];
    vws[idx] = vw[blockIdx.y * 768 + idx];
  }
  for (int idx = t; idx < QTOK * 192; idx += 256) {
    int ss = idx / 192, c = idx % 192;
    int s = s0 + ss, h = s / WSZ, wc = s % WSZ;
    int C = c0 + c;
    float acc = cb[C];
    #pragma unroll
    for (int kh = 0; kh < 3; ++kh) {
      int hh = h + kh - 1;
      if (hh < 0 || hh >= HS) continue;
      #pragma unroll
      for (int kw2 = 0; kw2 < 3; ++kw2) {
        int ww = wc + kw2 - 1;
        if (ww < 0 || ww >= WSZ) continue;
        acc += xin[(hh * WSZ + ww) * (2 * INNER) + C] * cw[C * 9 + kh * 3 + kw2];
      }
    }
    float sil = acc / (1.0f + __expf(-acc));
    xat[ss][c] = sil;
    xa[s * INNER + C] = sil;
    xmt[ss][c] = xin[s * (2 * INNER) + C];
  }
  __syncthreads();
  int ss = t & 15, cg = t >> 4;       // 16 tokens x 16 channel-groups
  int s = s0 + ss;
  #pragma unroll 4
  for (int k2 = 0; k2 < 12; ++k2) {
    int c = cg * 12 + k2;
    int nl = c >> 2, o = c & 3;
    const float* qwp = qws + nl * 16 + o * 4;
    const float* kwp = kws + nl * 16 + o * 4;
    const float* vwp = vws + nl * 16 + o * 4;
    float a0 = xat[ss][nl * 4 + 0], a1 = xat[ss][nl * 4 + 1];
    float a2 = xat[ss][nl * 4 + 2], a3 = xat[ss][nl * 4 + 3];
    float m0v = xmt[ss][nl * 4 + 0], m1v = xmt[ss][nl * 4 + 1];
    float m2v = xmt[ss][nl * 4 + 2], m3v = xmt[ss][nl * 4 + 3];
    int C = c0 + c;
    float qv = qb[C] + a0 * qwp[0] + a1 * qwp[1] + a2 * qwp[2] + a3 * qwp[3];
    float kv = kb[C] + a0 * kwp[0] + a1 * kwp[1] + a2 * kwp[2] + a3 * kwp[3];
    float vv = vb[C] + m0v * vwp[0] + m1v * vwp[1] + m2v * vwp[2] + m3v * vwp[3];
    ginT[C * SEQ + s]               = qv;
    ginT[(INNER + C) * SEQ + s]     = kv;
    ginT[(2 * INNER + C) * SEQ + s] = vv;
  }
}

// 3) gate GEMM: C[192,576] = W[192,1152] @ ginT[1152,576], K-split into 4
//    deterministic partial buffers pig/pfg[4][96][576].
#define GBM 16
#define GBN 64
#define GBK 32
#define GKS 4
#define GSL (GIN / GKS)   // 288
#define WPAD 20
__global__ __launch_bounds__(128) void k_gates(const float* __restrict__ ginT,
    const float* __restrict__ igw, const float* __restrict__ fgw,
    float* __restrict__ pig, float* __restrict__ pfg) {
  int m0 = blockIdx.x * GBM, s0 = blockIdx.y * GBN, ks = blockIdx.z;
  int k0 = ks * GSL;
  __shared__ float Ws[GBK * WPAD];  // [kk][r]
  __shared__ float Gs[GBK * GBN];   // [kk][ss]
  int t = threadIdx.x;
  const float* wbase = (m0 < NHEAD) ? (igw + m0 * GIN) : (fgw + (m0 - NHEAD) * GIN);
  int gm = t >> 4, gn = t & 15;
  float acc[2][4] = {{0.f,0.f,0.f,0.f},{0.f,0.f,0.f,0.f}};
  for (int kc = 0; kc < GSL; kc += GBK) {
    __syncthreads();
    for (int idx = t; idx < GBM * GBK; idx += 128) {
      int r = idx >> 5, kk = idx & 31;
      Ws[kk * WPAD + r] = wbase[r * GIN + k0 + kc + kk];
    }
    for (int idx = t; idx < GBK * GBN; idx += 128) {
      int kk = idx >> 6, ss = idx & 63;
      Gs[kk * GBN + ss] = ginT[(k0 + kc + kk) * SEQ + s0 + ss];
    }
    __syncthreads();
    #pragma unroll 8
    for (int kk = 0; kk < GBK; ++kk) {
      float2 wv = *(const float2*)&Ws[kk * WPAD + 2 * gm];
      float4 gv = *(const float4*)&Gs[kk * GBN + 4 * gn];
      acc[0][0] += wv.x * gv.x; acc[0][1] += wv.x * gv.y;
      acc[0][2] += wv.x * gv.z; acc[0][3] += wv.x * gv.w;
      acc[1][0] += wv.y * gv.x; acc[1][1] += wv.y * gv.y;
      acc[1][2] += wv.y * gv.z; acc[1][3] += wv.y * gv.w;
    }
  }
  #pragma unroll
  for (int i = 0; i < 2; ++i) {
    int m = m0 + 2 * gm + i;
    float* dst = (m < NHEAD) ? (pig + ks * NHEAD * SEQ + m * SEQ)
                             : (pfg + ks * NHEAD * SEQ + (m - NHEAD) * SEQ);
    *(float4*)&dst[s0 + 4 * gn] = make_float4(acc[i][0], acc[i][1], acc[i][2], acc[i][3]);
  }
}

// 4) mLSTM core: combine gate partials + biases, log-sigmoid, block-wide
//    sum-scan (lfc) and prefix-max scan, triangular accumulate, groupnorm.
__global__ __launch_bounds__(576) void k_mlstm(const float* __restrict__ ginT,
    const float* __restrict__ pig, const float* __restrict__ pfg,
    const float* __restrict__ igb, const float* __restrict__ fgb,
    const float* __restrict__ onw, float* __restrict__ hout) {
  int n = blockIdx.x, s = threadIdx.x;
  __shared__ float ks[SEQ][4], vs[SEQ][4], es[SEQ];
  __shared__ float bufA[SEQ], bufB[SEQ];
  const int HS4 = NHEAD * SEQ;
  int off = n * SEQ + s;
  float ai = igb[n] + pig[off] + pig[HS4 + off] + pig[2 * HS4 + off] + pig[3 * HS4 + off];
  float af = fgb[n] + pfg[off] + pfg[HS4 + off] + pfg[2 * HS4 + off] + pfg[3 * HS4 + off];
  float lf = (af >= 0.f) ? -log1pf(expf(-af)) : (af - log1pf(expf(af)));
  #pragma unroll
  for (int i = 0; i < 4; ++i) {
    ks[s][i] = ginT[(INNER + n * 4 + i) * SEQ + s] * 0.5f;   // k / sqrt(DH)
    vs[s][i] = ginT[(2 * INNER + n * 4 + i) * SEQ + s];
  }
  float q0 = ginT[(n * 4 + 0) * SEQ + s];
  float q1 = ginT[(n * 4 + 1) * SEQ + s];
  float q2 = ginT[(n * 4 + 2) * SEQ + s];
  float q3 = ginT[(n * 4 + 3) * SEQ + s];
  // inclusive sum-scan of lf -> lfs (cumulative log-forget)
  bufA[s] = lf;
  __syncthreads();
  float* src = bufA; float* dst = bufB;
  for (int o2 = 1; o2 < SEQ; o2 <<= 1) {
    float v = src[s];
    if (s >= o2) v += src[s - o2];
    dst[s] = v;
    __syncthreads();
    float* tmp = src; src = dst; dst = tmp;
  }
  float lfs = src[s];
  float e = ai - lfs;            // e[t] = ig[t] - lfc[t]
  es[s] = e;
  dst[s] = e;
  __syncthreads();
  // prefix-max scan of e -> pm
  src = dst; dst = (src == bufA) ? bufB : bufA;
  for (int o2 = 1; o2 < SEQ; o2 <<= 1) {
    float v = src[s];
    if (s >= o2) v = fmaxf(v, src[s - o2]);
    dst[s] = v;
    __syncthreads();
    float* tmp = src; src = dst; dst = tmp;
  }
  float pm = src[s];             // maxD = lfs + pm
  float csum = 0.f, h0 = 0.f, h1 = 0.f, h2 = 0.f, h3 = 0.f;
  for (int tt = 0; tt <= s; ++tt) {
    float d = __expf(es[tt] - pm);
    float c = (q0 * ks[tt][0] + q1 * ks[tt][1] + q2 * ks[tt][2] + q3 * ks[tt][3]) * d;
    csum += c;
    h0 += c * vs[tt][0]; h1 += c * vs[tt][1]; h2 += c * vs[tt][2]; h3 += c * vs[tt][3];
  }
  float norm = fmaxf(fabsf(csum), __expf(-(lfs + pm))) + 1e-6f;
  float r = 1.0f / norm;
  h0 *= r; h1 *= r; h2 *= r; h3 *= r;
  float mu = (h0 + h1 + h2 + h3) * 0.25f;
  float d0 = h0 - mu, d1 = h1 - mu, d2 = h2 - mu, d3 = h3 - mu;
  float var = (d0 * d0 + d1 * d1 + d2 * d2 + d3 * d3) * 0.25f;
  float inv = rsqrtf(var + 1e-5f);
  float* ho = hout + s * INNER + n * 4;
  ho[0] = d0 * inv * onw[n * 4];
  ho[1] = d1 * inv * onw[n * 4 + 1];
  ho[2] = d2 * inv * onw[n * 4 + 2];
  ho[3] = d3 * inv * onw[n * 4 + 3];
}

// 5) tiled GEMM, fused h2 epilogue-A: out = h2 @ down_w.T + down_b
#define DNA 20
#define DNB 36
__global__ __launch_bounds__(128) void k_down(const float* __restrict__ hmat,
    const float* __restrict__ xa, const float* __restrict__ xin,
    const float* __restrict__ skip, const float* __restrict__ dw,
    const float* __restrict__ db, float* __restrict__ out) {
  int m0 = blockIdx.x * 16, n0 = blockIdx.y * 32;
  __shared__ float As[INNER * DNA];   // [k][m]
  __shared__ float Bs[INNER * DNB];   // [k][o]
  int t = threadIdx.x;
  for (int idx = t; idx < 16 * INNER; idx += 128) {
    int r = idx / INNER, k = idx % INNER;
    int s = m0 + r;
    float z = xin[s * (2 * INNER) + INNER + k];
    float sil = z / (1.0f + __expf(-z));
    As[k * DNA + r] = (hmat[s * INNER + k] + skip[k] * xa[s * INNER + k]) * sil;
  }
  for (int idx = t; idx < 32 * INNER; idx += 128) {
    int r = idx / INNER, k = idx % INNER;
    Bs[k * DNB + r] = dw[(n0 + r) * INNER + k];
  }
  __syncthreads();
  int gm = t >> 4;        // 0..7  -> tokens 2gm..+1
  int gn = t & 15;        // 0..15 -> outputs 2gn..+1
  float acc[2][2];
  #pragma unroll
  for (int i = 0; i < 2; ++i)
    #pragma unroll
    for (int j = 0; j < 2; ++j) acc[i][j] = db[n0 + 2 * gn + j];
  #pragma unroll 4
  for (int kk = 0; kk < INNER; ++kk) {
    float2 a = *(const float2*)&As[kk * DNA + 2 * gm];
    float2 bv = *(const float2*)&Bs[kk * DNB + 2 * gn];
    acc[0][0] += a.x * bv.x; acc[0][1] += a.x * bv.y;
    acc[1][0] += a.y * bv.x; acc[1][1] += a.y * bv.y;
  }
  #pragma unroll
  for (int i = 0; i < 2; ++i) {
    float2 v = make_float2(acc[i][0], acc[i][1]);
    *(float2*)&out[(m0 + 2 * gm + i) * DIM + n0 + 2 * gn] = v;
  }
}

extern "C" void kernel_launch(void* const* d_in, const int* in_sizes, int n_in,
                              void* d_out, int out_size, void* d_ws, size_t ws_size,
                              hipStream_t stream) {
  const float* x      = (const float*)d_in[0];
  const float* ln_w   = (const float*)d_in[2];
  const float* ln_b   = (const float*)d_in[3];
  const float* up_w   = (const float*)d_in[4];
  const float* up_b   = (const float*)d_in[5];
  const float* q_w    = (const float*)d_in[8];
  const float* q_b    = (const float*)d_in[9];
  const float* k_w    = (const float*)d_in[10];
  const float* k_b    = (const float*)d_in[11];
  const float* v_w    = (const float*)d_in[12];
  const float* v_b    = (const float*)d_in[13];
  const float* conv_w = (const float*)d_in[14];
  const float* conv_b = (const float*)d_in[15];
  const float* ig_w   = (const float*)d_in[16];
  const float* ig_b   = (const float*)d_in[17];
  const float* fg_w   = (const float*)d_in[18];
  const float* fg_b   = (const float*)d_in[19];
  const float* onorm_w= (const float*)d_in[20];
  const float* skip   = (const float*)d_in[21];
  const float* down_w = (const float*)d_in[22];
  const float* down_b = (const float*)d_in[23];
  float* out = (float*)d_out;

  float* ws     = (float*)d_ws;
  float* xinner = ws;                       // 576*768
  float* xa     = xinner + SEQ * 2 * INNER; // 576*384
  float* ginT   = xa + SEQ * INNER;         // 1152*576
  float* pig    = ginT + GIN * SEQ;         // 4*96*576
  float* pfg    = pig + GKS * NHEAD * SEQ;  // 4*96*576
  float* hbuf   = pfg + GKS * NHEAD * SEQ;  // 576*384

  k_up   <<<dim3(9, 24), 256, 0, stream>>>(x, ln_w, ln_b, up_w, up_b, xinner);
  k_cqkv <<<dim3(36, 2), 256, 0, stream>>>(xinner, conv_w, conv_b,
                                           q_w, q_b, k_w, k_b, v_w, v_b, xa, ginT);
  k_gates<<<dim3(12, 9, GKS), 128, 0, stream>>>(ginT, ig_w, fg_w, pig, pfg);
  k_mlstm<<<NHEAD, SEQ, 0, stream>>>(ginT, pig, pfg, ig_b, fg_b, onorm_w, hbuf);
  k_down <<<dim3(36, 6), 128, 0, stream>>>(hbuf, xa, xinner, skip, down_w, down_b, out);
}

// Round 6
// 116.396 us; speedup vs baseline: 1.2642x; 1.2642x over previous
//
#include <hip/hip_runtime.h>
#include <math.h>

#define SEQ 576
#define DIM 192
#define INNER 384
#define NHEAD 96
#define HS 24
#define WSZ 24
#define GIN 1152

__device__ __forceinline__ float wave_reduce_sum(float v) {
  #pragma unroll
  for (int off = 32; off > 0; off >>= 1) v += __shfl_down(v, off);
  return __shfl(v, 0);
}

// 1) LayerNorm over DIM=192, one wave per row (coalesced)
__global__ __launch_bounds__(64) void k_ln(const float* __restrict__ x,
    const float* __restrict__ w, const float* __restrict__ b,
    float* __restrict__ xn) {
  int s = blockIdx.x, t = threadIdx.x;
  const float* xr = x + s * DIM;
  float a0 = xr[t], a1 = xr[t + 64], a2 = xr[t + 128];
  float mu = wave_reduce_sum(a0 + a1 + a2) * (1.0f / DIM);
  float d0 = a0 - mu, d1 = a1 - mu, d2 = a2 - mu;
  float var = wave_reduce_sum(d0 * d0 + d1 * d1 + d2 * d2) * (1.0f / DIM);
  float inv = rsqrtf(var + 1e-5f);
  float* o = xn + s * DIM;
  o[t]       = d0 * inv * w[t]       + b[t];
  o[t + 64]  = d1 * inv * w[t + 64]  + b[t + 64];
  o[t + 128] = d2 * inv * w[t + 128] + b[t + 128];
}

// 2) tiled GEMM: x_inner = xn @ up_w.T + up_b.  BM=64,BN=32,K=192 single-shot.
#define UPA 68
#define UPB 36
__global__ __launch_bounds__(256) void k_up(const float* __restrict__ xn,
    const float* __restrict__ w, const float* __restrict__ b,
    float* __restrict__ out) {
  int m0 = blockIdx.x * 64, n0 = blockIdx.y * 32;
  __shared__ float As[DIM * UPA];   // [k][m]
  __shared__ float Bs[DIM * UPB];   // [k][o]
  int t = threadIdx.x;
  for (int idx = t; idx < 64 * 48; idx += 256) {
    int r = idx / 48, k4 = idx % 48;
    float4 v = *(const float4*)&xn[(m0 + r) * DIM + 4 * k4];
    As[(4 * k4 + 0) * UPA + r] = v.x;
    As[(4 * k4 + 1) * UPA + r] = v.y;
    As[(4 * k4 + 2) * UPA + r] = v.z;
    As[(4 * k4 + 3) * UPA + r] = v.w;
  }
  for (int idx = t; idx < 32 * 48; idx += 256) {
    int r = idx / 48, k4 = idx % 48;
    float4 v = *(const float4*)&w[(n0 + r) * DIM + 4 * k4];
    Bs[(4 * k4 + 0) * UPB + r] = v.x;
    Bs[(4 * k4 + 1) * UPB + r] = v.y;
    Bs[(4 * k4 + 2) * UPB + r] = v.z;
    Bs[(4 * k4 + 3) * UPB + r] = v.w;
  }
  __syncthreads();
  int gm = t >> 4;        // 0..15 -> tokens 4gm..+3
  int gn = t & 15;        // 0..15 -> outputs 2gn..+1
  float acc[4][2];
  #pragma unroll
  for (int i = 0; i < 4; ++i)
    #pragma unroll
    for (int j = 0; j < 2; ++j) acc[i][j] = b[n0 + 2 * gn + j];
  #pragma unroll 4
  for (int kk = 0; kk < DIM; ++kk) {
    float4 a = *(const float4*)&As[kk * UPA + 4 * gm];
    float2 bv = *(const float2*)&Bs[kk * UPB + 2 * gn];
    acc[0][0] += a.x * bv.x; acc[0][1] += a.x * bv.y;
    acc[1][0] += a.y * bv.x; acc[1][1] += a.y * bv.y;
    acc[2][0] += a.z * bv.x; acc[2][1] += a.z * bv.y;
    acc[3][0] += a.w * bv.x; acc[3][1] += a.w * bv.y;
  }
  #pragma unroll
  for (int i = 0; i < 4; ++i) {
    float2 v = make_float2(acc[i][0], acc[i][1]);
    *(float2*)&out[(m0 + 4 * gm + i) * (2 * INNER) + n0 + 2 * gn] = v;
  }
}

// 3) fused conv3x3+SiLU+qkv, block per token (576 x 384thr, 6 waves)
__global__ __launch_bounds__(384) void k_cqkv(const float* __restrict__ xin,
    const float* __restrict__ cw, const float* __restrict__ cb,
    const float* __restrict__ qw, const float* __restrict__ qb,
    const float* __restrict__ kw, const float* __restrict__ kb,
    const float* __restrict__ vw, const float* __restrict__ vb,
    float* __restrict__ xa, float* __restrict__ ginT) {
  int s = blockIdx.x, t = threadIdx.x;
  int h = s / WSZ, wc = s % WSZ;
  __shared__ float xat[INNER], xmt[INNER];
  float acc = cb[t];
  #pragma unroll
  for (int kh = 0; kh < 3; ++kh) {
    int hh = h + kh - 1;
    if (hh < 0 || hh >= HS) continue;
    #pragma unroll
    for (int kw2 = 0; kw2 < 3; ++kw2) {
      int ww = wc + kw2 - 1;
      if (ww < 0 || ww >= WSZ) continue;
      acc += xin[(hh * WSZ + ww) * (2 * INNER) + t] * cw[t * 9 + kh * 3 + kw2];
    }
  }
  float sil = acc / (1.0f + __expf(-acc));
  xat[t] = sil;
  xa[s * INNER + t] = sil;
  xmt[t] = xin[s * (2 * INNER) + t];
  __syncthreads();
  int n = t >> 2, o = t & 3;
  const float* xah = xat + n * 4;
  const float* xmh = xmt + n * 4;
  float q = qb[t], k = kb[t], v = vb[t];
  #pragma unroll
  for (int i = 0; i < 4; ++i) {
    float xq = xah[i], xm = xmh[i];
    q += xq * qw[n * 16 + o * 4 + i];
    k += xq * kw[n * 16 + o * 4 + i];
    v += xm * vw[n * 16 + o * 4 + i];
  }
  ginT[t * SEQ + s]               = q;
  ginT[(INNER + t) * SEQ + s]     = k;
  ginT[(2 * INNER + t) * SEQ + s] = v;
}

// 4) gate GEMM: C[192,576] = W[192,1152] @ ginT, K-split 4, single-shot stage.
//    grid (6 m-tiles of 32, 9 s-tiles of 64, 4 k-slices), 256 thr, LDS 115KB.
#define GBK 288
#define GKS 4
#define WP 36
__global__ __launch_bounds__(256) void k_gates(const float* __restrict__ ginT,
    const float* __restrict__ igw, const float* __restrict__ fgw,
    float* __restrict__ pig, float* __restrict__ pfg) {
  int bx = blockIdx.x, s0 = blockIdx.y * 64, ks = blockIdx.z;
  int k0 = ks * GBK;
  bool isig = bx < 3;
  int m0 = (isig ? bx : bx - 3) * 32;
  const float* wb = (isig ? igw : fgw) + m0 * GIN;
  __shared__ float Ws[GBK * WP];   // [kk][r] 41.5KB
  __shared__ float Gs[GBK * 64];   // [kk][ss] 73.7KB
  int t = threadIdx.x;
  for (int idx = t; idx < 32 * 72; idx += 256) {
    int r = idx / 72, k4 = idx % 72;
    float4 v = *(const float4*)&wb[r * GIN + k0 + 4 * k4];
    Ws[(4 * k4 + 0) * WP + r] = v.x;
    Ws[(4 * k4 + 1) * WP + r] = v.y;
    Ws[(4 * k4 + 2) * WP + r] = v.z;
    Ws[(4 * k4 + 3) * WP + r] = v.w;
  }
  for (int idx = t; idx < GBK * 16; idx += 256) {
    int kk = idx / 16, s4 = idx % 16;
    *(float4*)&Gs[kk * 64 + 4 * s4] =
        *(const float4*)&ginT[(k0 + kk) * SEQ + s0 + 4 * s4];
  }
  __syncthreads();
  int gm = t >> 4, gn = t & 15;    // 2m x 4n per thread
  float acc[2][4] = {{0.f,0.f,0.f,0.f},{0.f,0.f,0.f,0.f}};
  #pragma unroll 4
  for (int kk = 0; kk < GBK; ++kk) {
    float2 wv = *(const float2*)&Ws[kk * WP + 2 * gm];
    float4 gv = *(const float4*)&Gs[kk * 64 + 4 * gn];
    acc[0][0] += wv.x * gv.x; acc[0][1] += wv.x * gv.y;
    acc[0][2] += wv.x * gv.z; acc[0][3] += wv.x * gv.w;
    acc[1][0] += wv.y * gv.x; acc[1][1] += wv.y * gv.y;
    acc[1][2] += wv.y * gv.z; acc[1][3] += wv.y * gv.w;
  }
  float* dstp = (isig ? pig : pfg) + ks * NHEAD * SEQ;
  #pragma unroll
  for (int i = 0; i < 2; ++i) {
    int mm = m0 + 2 * gm + i;
    *(float4*)&dstp[mm * SEQ + s0 + 4 * gn] =
        make_float4(acc[i][0], acc[i][1], acc[i][2], acc[i][3]);
  }
}

// 5) combine partials + biases, log-sigmoid, cumsum + prefix-max
//    -> es[t]=ig-lfc, pm[s]=prefixmax(es), mx[s]=lfc+pm
__global__ __launch_bounds__(64) void k_scan(const float* __restrict__ pig,
    const float* __restrict__ pfg, const float* __restrict__ igb,
    const float* __restrict__ fgb, float* __restrict__ es_g,
    float* __restrict__ pm_g, float* __restrict__ mx_g) {
  int n = blockIdx.x, t = threadIdx.x;
  float bi = igb[n], bf = fgb[n];
  float carryS = 0.f, carryM = -3.0e38f;
  const int H4 = NHEAD * SEQ;
  for (int c = 0; c < SEQ / 64; ++c) {
    int off = n * SEQ + c * 64 + t;
    float ai = bi + pig[off] + pig[off + H4] + pig[off + 2 * H4] + pig[off + 3 * H4];
    float af = bf + pfg[off] + pfg[off + H4] + pfg[off + 2 * H4] + pfg[off + 3 * H4];
    float lf = (af >= 0.f) ? -log1pf(expf(-af)) : (af - log1pf(expf(af)));
    float v = lf;
    #pragma unroll
    for (int o2 = 1; o2 < 64; o2 <<= 1) {
      float u = __shfl_up(v, o2);
      if (t >= o2) v += u;
    }
    v += carryS;
    carryS = __shfl(v, 63);
    float e = ai - v;
    es_g[off] = e;
    float m = e;
    #pragma unroll
    for (int o2 = 1; o2 < 64; o2 <<= 1) {
      float u = __shfl_up(m, o2);
      if (t >= o2) m = fmaxf(m, u);
    }
    m = fmaxf(m, carryM);
    carryM = __shfl(m, 63);
    pm_g[off] = m;
    mx_g[off] = v + m;
  }
}

// 6) mLSTM triangular accumulate + groupnorm. grid (96 heads, 2 seq-halves).
__global__ __launch_bounds__(320) void k_mlstm(const float* __restrict__ ginT,
    const float* __restrict__ es_g, const float* __restrict__ pm_g,
    const float* __restrict__ mx_g, const float* __restrict__ onw,
    float* __restrict__ hout) {
  int n = blockIdx.x, hh = blockIdx.y, t = threadIdx.x;
  int cnt = 288 * (hh + 1);
  __shared__ float ks[SEQ][4], vs[SEQ][4], es[SEQ];
  for (int tt = t; tt < cnt; tt += 320) {
    float a0 = ginT[(INNER + n * 4 + 0) * SEQ + tt] * 0.5f;
    float a1 = ginT[(INNER + n * 4 + 1) * SEQ + tt] * 0.5f;
    float a2 = ginT[(INNER + n * 4 + 2) * SEQ + tt] * 0.5f;
    float a3 = ginT[(INNER + n * 4 + 3) * SEQ + tt] * 0.5f;
    *(float4*)&ks[tt][0] = make_float4(a0, a1, a2, a3);
    float b0 = ginT[(2 * INNER + n * 4 + 0) * SEQ + tt];
    float b1 = ginT[(2 * INNER + n * 4 + 1) * SEQ + tt];
    float b2 = ginT[(2 * INNER + n * 4 + 2) * SEQ + tt];
    float b3 = ginT[(2 * INNER + n * 4 + 3) * SEQ + tt];
    *(float4*)&vs[tt][0] = make_float4(b0, b1, b2, b3);
    es[tt] = es_g[n * SEQ + tt];
  }
  __syncthreads();
  if (t < 288) {
    int s = 288 * hh + t;
    float q0 = ginT[(n * 4 + 0) * SEQ + s];
    float q1 = ginT[(n * 4 + 1) * SEQ + s];
    float q2 = ginT[(n * 4 + 2) * SEQ + s];
    float q3 = ginT[(n * 4 + 3) * SEQ + s];
    float pm = pm_g[n * SEQ + s];
    float mx = mx_g[n * SEQ + s];
    float csum = 0.f, h0 = 0.f, h1 = 0.f, h2 = 0.f, h3 = 0.f;
    for (int tt = 0; tt <= s; ++tt) {
      float d = __expf(es[tt] - pm);
      float c = (q0 * ks[tt][0] + q1 * ks[tt][1] + q2 * ks[tt][2] + q3 * ks[tt][3]) * d;
      csum += c;
      h0 += c * vs[tt][0]; h1 += c * vs[tt][1]; h2 += c * vs[tt][2]; h3 += c * vs[tt][3];
    }
    float norm = fmaxf(fabsf(csum), __expf(-mx)) + 1e-6f;
    float r = 1.0f / norm;
    h0 *= r; h1 *= r; h2 *= r; h3 *= r;
    float mu = (h0 + h1 + h2 + h3) * 0.25f;
    float d0 = h0 - mu, d1 = h1 - mu, d2 = h2 - mu, d3 = h3 - mu;
    float var = (d0 * d0 + d1 * d1 + d2 * d2 + d3 * d3) * 0.25f;
    float inv = rsqrtf(var + 1e-5f);
    *(float4*)&hout[s * INNER + n * 4] = make_float4(
        d0 * inv * onw[n * 4 + 0], d1 * inv * onw[n * 4 + 1],
        d2 * inv * onw[n * 4 + 2], d3 * inv * onw[n * 4 + 3]);
  }
}

// 7) tiled GEMM, fused h2 epilogue-A: out = h2 @ down_w.T + down_b
#define DNA 20
#define DNB 36
__global__ __launch_bounds__(128) void k_down(const float* __restrict__ hmat,
    const float* __restrict__ xa, const float* __restrict__ xin,
    const float* __restrict__ skip, const float* __restrict__ dw,
    const float* __restrict__ db, float* __restrict__ out) {
  int m0 = blockIdx.x * 16, n0 = blockIdx.y * 32;
  __shared__ float As[INNER * DNA];   // [k][m]
  __shared__ float Bs[INNER * DNB];   // [k][o]
  int t = threadIdx.x;
  for (int idx = t; idx < 16 * 96; idx += 128) {
    int r = idx / 96, k4 = idx % 96;
    int s = m0 + r;
    float4 zv = *(const float4*)&xin[s * (2 * INNER) + INNER + 4 * k4];
    float4 hm = *(const float4*)&hmat[s * INNER + 4 * k4];
    float4 xv = *(const float4*)&xa[s * INNER + 4 * k4];
    float4 sk = *(const float4*)&skip[4 * k4];
    float z, sil;
    z = zv.x; sil = z / (1.0f + __expf(-z));
    As[(4 * k4 + 0) * DNA + r] = (hm.x + sk.x * xv.x) * sil;
    z = zv.y; sil = z / (1.0f + __expf(-z));
    As[(4 * k4 + 1) * DNA + r] = (hm.y + sk.y * xv.y) * sil;
    z = zv.z; sil = z / (1.0f + __expf(-z));
    As[(4 * k4 + 2) * DNA + r] = (hm.z + sk.z * xv.z) * sil;
    z = zv.w; sil = z / (1.0f + __expf(-z));
    As[(4 * k4 + 3) * DNA + r] = (hm.w + sk.w * xv.w) * sil;
  }
  for (int idx = t; idx < 32 * 96; idx += 128) {
    int r = idx / 96, k4 = idx % 96;
    float4 v = *(const float4*)&dw[(n0 + r) * INNER + 4 * k4];
    Bs[(4 * k4 + 0) * DNB + r] = v.x;
    Bs[(4 * k4 + 1) * DNB + r] = v.y;
    Bs[(4 * k4 + 2) * DNB + r] = v.z;
    Bs[(4 * k4 + 3) * DNB + r] = v.w;
  }
  __syncthreads();
  int gm = t >> 4;        // 0..7  -> tokens 2gm..+1
  int gn = t & 15;        // 0..15 -> outputs 2gn..+1
  float acc[2][2];
  #pragma unroll
  for (int i = 0; i < 2; ++i)
    #pragma unroll
    for (int j = 0; j < 2; ++j) acc[i][j] = db[n0 + 2 * gn + j];
  #pragma unroll 4
  for (int kk = 0; kk < INNER; ++kk) {
    float2 a = *(const float2*)&As[kk * DNA + 2 * gm];
    float2 bv = *(const float2*)&Bs[kk * DNB + 2 * gn];
    acc[0][0] += a.x * bv.x; acc[0][1] += a.x * bv.y;
    acc[1][0] += a.y * bv.x; acc[1][1] += a.y * bv.y;
  }
  #pragma unroll
  for (int i = 0; i < 2; ++i) {
    float2 v = make_float2(acc[i][0], acc[i][1]);
    *(float2*)&out[(m0 + 2 * gm + i) * DIM + n0 + 2 * gn] = v;
  }
}

extern "C" void kernel_launch(void* const* d_in, const int* in_sizes, int n_in,
                              void* d_out, int out_size, void* d_ws, size_t ws_size,
                              hipStream_t stream) {
  const float* x      = (const float*)d_in[0];
  const float* ln_w   = (const float*)d_in[2];
  const float* ln_b   = (const float*)d_in[3];
  const float* up_w   = (const float*)d_in[4];
  const float* up_b   = (const float*)d_in[5];
  const float* q_w    = (const float*)d_in[8];
  const float* q_b    = (const float*)d_in[9];
  const float* k_w    = (const float*)d_in[10];
  const float* k_b    = (const float*)d_in[11];
  const float* v_w    = (const float*)d_in[12];
  const float* v_b    = (const float*)d_in[13];
  const float* conv_w = (const float*)d_in[14];
  const float* conv_b = (const float*)d_in[15];
  const float* ig_w   = (const float*)d_in[16];
  const float* ig_b   = (const float*)d_in[17];
  const float* fg_w   = (const float*)d_in[18];
  const float* fg_b   = (const float*)d_in[19];
  const float* onorm_w= (const float*)d_in[20];
  const float* skip   = (const float*)d_in[21];
  const float* down_w = (const float*)d_in[22];
  const float* down_b = (const float*)d_in[23];
  float* out = (float*)d_out;

  float* ws     = (float*)d_ws;
  float* xn     = ws;                       // 576*192
  float* xinner = xn + SEQ * DIM;           // 576*768
  float* xa     = xinner + SEQ * 2 * INNER; // 576*384
  float* ginT   = xa + SEQ * INNER;         // 1152*576
  float* pig    = ginT + GIN * SEQ;         // 4*96*576
  float* pfg    = pig + GKS * NHEAD * SEQ;  // 4*96*576
  float* es_g   = pfg + GKS * NHEAD * SEQ;  // 96*576
  float* pm_g   = es_g + NHEAD * SEQ;       // 96*576
  float* mx_g   = pm_g + NHEAD * SEQ;       // 96*576
  float* hbuf   = mx_g + NHEAD * SEQ;       // 576*384

  k_ln   <<<SEQ, 64, 0, stream>>>(x, ln_w, ln_b, xn);
  k_up   <<<dim3(9, 24), 256, 0, stream>>>(xn, up_w, up_b, xinner);
  k_cqkv <<<SEQ, 384, 0, stream>>>(xinner, conv_w, conv_b,
                                   q_w, q_b, k_w, k_b, v_w, v_b, xa, ginT);
  k_gates<<<dim3(6, 9, GKS), 256, 0, stream>>>(ginT, ig_w, fg_w, pig, pfg);
  k_scan <<<NHEAD, 64, 0, stream>>>(pig, pfg, ig_b, fg_b, es_g, pm_g, mx_g);
  k_mlstm<<<dim3(NHEAD, 2), 320, 0, stream>>>(ginT, es_g, pm_g, mx_g, onorm_w, hbuf);
  k_down <<<dim3(36, 6), 128, 0, stream>>>(hbuf, xa, xinner, skip, down_w, down_b, out);
}